// Round 11
// baseline (86.673 us; speedup 1.0000x reference)
//
#include <hip/hip_runtime.h>
#include <math.h>

// out[d] = s_ho*h_o[d] + s_h*h[d]; per-token scalars from 6 dot-reductions.
// Occupancy-first geometry: 512 threads/block, 4 dims/lane (tables = 24 VGPR
// instead of 48), h NOT held in registers across phases (phase 2 re-reads it
// from L2/L3), no h_o preload. TLP (target 6-8 waves/SIMD) hides latency the
// way the 6.3TB/s copy ubench does, instead of per-thread load depth that the
// register budget could never actually hold (R9/R10: VGPR=108 proved the
// "full preload" never materialized). Two barriers, both placed where no
// useful loads are in flight; phase 2 is a barrier-free ld/ld/fma/st stream.

constexpr int D    = 2048;
constexpr int RATE = 4;
constexpr float EPS = 1e-5f;
constexpr int TPB  = 8;    // tokens per block
constexpr int NT   = 512;  // threads per block; lane owns D/NT = 4 dims

__device__ __forceinline__ float fast_tanh(float x) {
    const float e = __expf(2.0f * x);
    return 1.0f - 2.0f / (e + 1.0f);
}

template<int CTRL>
__device__ __forceinline__ float dpp_add(float x) {
    int m = __builtin_amdgcn_update_dpp(0, __float_as_int(x), CTRL, 0xf, 0xf, true);
    return x + __int_as_float(m);
}

// After this, lane 63 holds the 64-lane sum.
__device__ __forceinline__ float wave_sum_lane63(float x) {
    x = dpp_add<0x111>(x);  // row_shr:1
    x = dpp_add<0x112>(x);  // row_shr:2
    x = dpp_add<0x114>(x);  // row_shr:4
    x = dpp_add<0x118>(x);  // row_shr:8
    x = dpp_add<0x142>(x);  // row_bcast:15
    x = dpp_add<0x143>(x);  // row_bcast:31
    return x;
}

__global__ __launch_bounds__(NT, 6) void hyperconn_kernel(
    const float* __restrict__ h,
    const float* __restrict__ h_o,
    const float* __restrict__ sa,    // [4][5]
    const float* __restrict__ sb,    // [4]
    const float* __restrict__ fa,    // [2048][5]
    const float* __restrict__ a_sc,  // [1]
    const float* __restrict__ fb,    // [2048]
    const float* __restrict__ b_sc,  // [1]
    const float* __restrict__ w,     // [2048]
    float* __restrict__ out)
{
    const int tid  = threadIdx.x;          // 0..511
    const int d0   = tid * 4;
    const int wave = tid >> 6;             // 0..7
    const size_t t0 = (size_t)blockIdx.x * TPB;

    // ---- per-block constant tables: 4 dims/lane -> 24 VGPR total
    const float4 wq  = *reinterpret_cast<const float4*>(w + d0);
    const float wv[4] = {wq.x, wq.y, wq.z, wq.w};
    float fav[16];   // fa[d0+j][1..4]
    {
        float tmp[20];
        #pragma unroll
        for (int q = 0; q < 5; ++q) {
            float4 t = *reinterpret_cast<const float4*>(fa + (size_t)d0 * 5 + q * 4);
            tmp[q*4+0]=t.x; tmp[q*4+1]=t.y; tmp[q*4+2]=t.z; tmp[q*4+3]=t.w;
        }
        #pragma unroll
        for (int j = 0; j < 4; ++j)
            #pragma unroll
            for (int c = 0; c < 4; ++c)
                fav[j*4+c] = tmp[j*5 + 1 + c];
    }
    const float4 fbq = *reinterpret_cast<const float4*>(fb + d0);
    const float fbv[4] = {fbq.x, fbq.y, fbq.z, fbq.w};

    const float a4 = a_sc[0] * (float)RATE;
    const float b4 = b_sc[0] * (float)RATE;
    float cs = 0.f;
    #pragma unroll
    for (int r = 0; r < RATE; ++r)
        #pragma unroll
        for (int c = 1; c <= RATE; ++c)
            cs += sa[r * (RATE + 1) + c];
    const float sbsum = sb[0] + sb[1] + sb[2] + sb[3];

    __shared__ float  red[TPB][48];   // [token][wave*6+k], 8 waves
    __shared__ float2 s2[TPB];        // finalized (s_h, s_ho) per token

    // ---- phase 1: stream h once, reduce per token (no barriers inside)
    #pragma unroll
    for (int i = 0; i < TPB; ++i) {
        const float4 hq = *reinterpret_cast<const float4*>(h + (t0 + i) * D + d0);
        const float hv[4] = {hq.x, hq.y, hq.z, hq.w};
        float acc[6] = {0.f, 0.f, 0.f, 0.f, 0.f, 0.f};
        #pragma unroll
        for (int j = 0; j < 4; ++j) {
            const float x  = hv[j];
            const float xw = x * wv[j];
            acc[0] = fmaf(x,  x,          acc[0]);
            acc[1] = fmaf(xw, fav[j*4+0], acc[1]);
            acc[2] = fmaf(xw, fav[j*4+1], acc[2]);
            acc[3] = fmaf(xw, fav[j*4+2], acc[3]);
            acc[4] = fmaf(xw, fav[j*4+3], acc[4]);
            acc[5] = fmaf(xw, fbv[j],     acc[5]);
        }
        #pragma unroll
        for (int k = 0; k < 6; ++k) acc[k] = wave_sum_lane63(acc[k]);
        if ((tid & 63) == 63) {
            #pragma unroll
            for (int k = 0; k < 6; ++k) red[i][wave * 6 + k] = acc[k];
        }
    }

    __syncthreads();

    // ---- finalize per-token scalars (8 threads), before phase-2 loads issue
    if (tid < TPB) {
        float tot[6] = {0.f, 0.f, 0.f, 0.f, 0.f, 0.f};
        #pragma unroll
        for (int v = 0; v < 8; ++v)
            #pragma unroll
            for (int k = 0; k < 6; ++k)
                tot[k] += red[tid][v * 6 + k];
        const float rms  = rsqrtf(tot[0] * (1.0f / (float)D) + EPS);
        const float s_h  = a4 * (fast_tanh(tot[1] * rms) + fast_tanh(tot[2] * rms) +
                                 fast_tanh(tot[3] * rms) + fast_tanh(tot[4] * rms)) + cs;
        const float s_ho = b4 * fast_tanh(tot[5] * rms) + sbsum;
        s2[tid] = make_float2(s_h, s_ho);
    }

    __syncthreads();

    // ---- phase 2: barrier-free ld/ld/fma/st stream; h re-read hits L2/L3
    #pragma unroll
    for (int i = 0; i < TPB; ++i) {
        const float2 s = s2[i];           // uniform broadcast
        const size_t base = (t0 + i) * D + d0;
        const float4 hq = *reinterpret_cast<const float4*>(h   + base);
        const float4 oq = *reinterpret_cast<const float4*>(h_o + base);
        float4 r;
        r.x = fmaf(s.y, oq.x, s.x * hq.x);
        r.y = fmaf(s.y, oq.y, s.x * hq.y);
        r.z = fmaf(s.y, oq.z, s.x * hq.z);
        r.w = fmaf(s.y, oq.w, s.x * hq.w);
        *reinterpret_cast<float4*>(out + base) = r;
    }
}

extern "C" void kernel_launch(void* const* d_in, const int* in_sizes, int n_in,
                              void* d_out, int out_size, void* d_ws, size_t ws_size,
                              hipStream_t stream) {
    const float* h    = (const float*)d_in[0];
    const float* h_o  = (const float*)d_in[1];
    const float* sa   = (const float*)d_in[2];
    const float* sb   = (const float*)d_in[3];
    const float* fa   = (const float*)d_in[4];
    const float* a_sc = (const float*)d_in[5];
    const float* fb   = (const float*)d_in[6];
    const float* b_sc = (const float*)d_in[7];
    const float* w    = (const float*)d_in[8];
    float* out = (float*)d_out;

    const int ntok   = in_sizes[0] / D;       // B*L = 16384
    const int blocks = ntok / TPB;            // 2048
    hyperconn_kernel<<<blocks, NT, 0, stream>>>(h, h_o, sa, sb, fa, a_sc, fb, b_sc, w, out);
}

// Round 12
// 79.678 us; speedup vs baseline: 1.0878x; 1.0878x over previous
//
#include <hip/hip_runtime.h>
#include <math.h>

// out[d] = s_ho*h_o[d] + s_h*h[d]; per-token scalars from 6 dot-reductions.
// R11 geometry (512 thr, 4 dims/lane, DPP reduce, 2 barriers) + h kept in
// registers across the barrier (R11's h re-read cost +62MB real HBM FETCH).
// R10 proved 402MB @ low occ = 4.9 TB/s; R11 proved high occ sustains 6.2
// TB/s logical but wasted 134MB. This kernel: 402MB at high occupancy.

constexpr int D    = 2048;
constexpr int RATE = 4;
constexpr float EPS = 1e-5f;
constexpr int TPB  = 8;    // tokens per block
constexpr int NT   = 512;  // threads per block; lane owns D/NT = 4 dims

__device__ __forceinline__ float fast_tanh(float x) {
    const float e = __expf(2.0f * x);
    return 1.0f - 2.0f / (e + 1.0f);
}

template<int CTRL>
__device__ __forceinline__ float dpp_add(float x) {
    int m = __builtin_amdgcn_update_dpp(0, __float_as_int(x), CTRL, 0xf, 0xf, true);
    return x + __int_as_float(m);
}

// After this, lane 63 holds the 64-lane sum.
__device__ __forceinline__ float wave_sum_lane63(float x) {
    x = dpp_add<0x111>(x);  // row_shr:1
    x = dpp_add<0x112>(x);  // row_shr:2
    x = dpp_add<0x114>(x);  // row_shr:4
    x = dpp_add<0x118>(x);  // row_shr:8
    x = dpp_add<0x142>(x);  // row_bcast:15
    x = dpp_add<0x143>(x);  // row_bcast:31
    return x;
}

__global__ __launch_bounds__(NT, 4) void hyperconn_kernel(
    const float* __restrict__ h,
    const float* __restrict__ h_o,
    const float* __restrict__ sa,    // [4][5]
    const float* __restrict__ sb,    // [4]
    const float* __restrict__ fa,    // [2048][5]
    const float* __restrict__ a_sc,  // [1]
    const float* __restrict__ fb,    // [2048]
    const float* __restrict__ b_sc,  // [1]
    const float* __restrict__ w,     // [2048]
    float* __restrict__ out)
{
    const int tid  = threadIdx.x;          // 0..511
    const int d0   = tid * 4;
    const int wave = tid >> 6;             // 0..7
    const size_t t0 = (size_t)blockIdx.x * TPB;

    // ---- h for all 8 tokens -> registers (32 VGPR), loads issued up front
    float4 hA[TPB];
    #pragma unroll
    for (int i = 0; i < TPB; ++i)
        hA[i] = *reinterpret_cast<const float4*>(h + (t0 + i) * D + d0);

    // ---- per-block constant tables: 4 dims/lane -> 24 VGPR total
    const float4 wq  = *reinterpret_cast<const float4*>(w + d0);
    const float wv[4] = {wq.x, wq.y, wq.z, wq.w};
    float fav[16];   // fa[d0+j][1..4]
    {
        float tmp[20];
        #pragma unroll
        for (int q = 0; q < 5; ++q) {
            float4 t = *reinterpret_cast<const float4*>(fa + (size_t)d0 * 5 + q * 4);
            tmp[q*4+0]=t.x; tmp[q*4+1]=t.y; tmp[q*4+2]=t.z; tmp[q*4+3]=t.w;
        }
        #pragma unroll
        for (int j = 0; j < 4; ++j)
            #pragma unroll
            for (int c = 0; c < 4; ++c)
                fav[j*4+c] = tmp[j*5 + 1 + c];
    }
    const float4 fbq = *reinterpret_cast<const float4*>(fb + d0);
    const float fbv[4] = {fbq.x, fbq.y, fbq.z, fbq.w};

    const float a4 = a_sc[0] * (float)RATE;
    const float b4 = b_sc[0] * (float)RATE;
    float cs = 0.f;
    #pragma unroll
    for (int r = 0; r < RATE; ++r)
        #pragma unroll
        for (int c = 1; c <= RATE; ++c)
            cs += sa[r * (RATE + 1) + c];
    const float sbsum = sb[0] + sb[1] + sb[2] + sb[3];

    __shared__ float  red[TPB][48];   // [token][wave*6+k], 8 waves
    __shared__ float2 s2[TPB];        // finalized (s_h, s_ho) per token

    // ---- phase 1: reduce per token from registers (no barriers inside)
    #pragma unroll
    for (int i = 0; i < TPB; ++i) {
        const float hv[4] = {hA[i].x, hA[i].y, hA[i].z, hA[i].w};
        float acc[6] = {0.f, 0.f, 0.f, 0.f, 0.f, 0.f};
        #pragma unroll
        for (int j = 0; j < 4; ++j) {
            const float x  = hv[j];
            const float xw = x * wv[j];
            acc[0] = fmaf(x,  x,          acc[0]);
            acc[1] = fmaf(xw, fav[j*4+0], acc[1]);
            acc[2] = fmaf(xw, fav[j*4+1], acc[2]);
            acc[3] = fmaf(xw, fav[j*4+2], acc[3]);
            acc[4] = fmaf(xw, fav[j*4+3], acc[4]);
            acc[5] = fmaf(xw, fbv[j],     acc[5]);
        }
        #pragma unroll
        for (int k = 0; k < 6; ++k) acc[k] = wave_sum_lane63(acc[k]);
        if ((tid & 63) == 63) {
            #pragma unroll
            for (int k = 0; k < 6; ++k) red[i][wave * 6 + k] = acc[k];
        }
    }

    __syncthreads();

    // ---- finalize per-token scalars (8 threads)
    if (tid < TPB) {
        float tot[6] = {0.f, 0.f, 0.f, 0.f, 0.f, 0.f};
        #pragma unroll
        for (int v = 0; v < 8; ++v)
            #pragma unroll
            for (int k = 0; k < 6; ++k)
                tot[k] += red[tid][v * 6 + k];
        const float rms  = rsqrtf(tot[0] * (1.0f / (float)D) + EPS);
        const float s_h  = a4 * (fast_tanh(tot[1] * rms) + fast_tanh(tot[2] * rms) +
                                 fast_tanh(tot[3] * rms) + fast_tanh(tot[4] * rms)) + cs;
        const float s_ho = b4 * fast_tanh(tot[5] * rms) + sbsum;
        s2[tid] = make_float2(s_h, s_ho);
    }

    __syncthreads();

    // ---- phase 2: h_o stream + fma + store; h already in registers
    #pragma unroll
    for (int i = 0; i < TPB; ++i) {
        const float2 s = s2[i];           // uniform broadcast
        const size_t base = (t0 + i) * D + d0;
        const float4 oq = *reinterpret_cast<const float4*>(h_o + base);
        float4 r;
        r.x = fmaf(s.y, oq.x, s.x * hA[i].x);
        r.y = fmaf(s.y, oq.y, s.x * hA[i].y);
        r.z = fmaf(s.y, oq.z, s.x * hA[i].z);
        r.w = fmaf(s.y, oq.w, s.x * hA[i].w);
        *reinterpret_cast<float4*>(out + base) = r;
    }
}

extern "C" void kernel_launch(void* const* d_in, const int* in_sizes, int n_in,
                              void* d_out, int out_size, void* d_ws, size_t ws_size,
                              hipStream_t stream) {
    const float* h    = (const float*)d_in[0];
    const float* h_o  = (const float*)d_in[1];
    const float* sa   = (const float*)d_in[2];
    const float* sb   = (const float*)d_in[3];
    const float* fa   = (const float*)d_in[4];
    const float* a_sc = (const float*)d_in[5];
    const float* fb   = (const float*)d_in[6];
    const float* b_sc = (const float*)d_in[7];
    const float* w    = (const float*)d_in[8];
    float* out = (float*)d_out;

    const int ntok   = in_sizes[0] / D;       // B*L = 16384
    const int blocks = ntok / TPB;            // 2048
    hyperconn_kernel<<<blocks, NT, 0, stream>>>(h, h_o, sa, sb, fa, a_sc, fb, b_sc, w, out);
}